// Round 14
// baseline (142.209 us; speedup 1.0000x reference)
//
#include <hip/hip_runtime.h>
#include <math.h>

#define B_   8
#define S_   1024
#define NXc  768
#define H_   12
#define HDc  64
#define M_   (B_*S_)        // 8192
#define NQKV (3*NXc)        // 2304

typedef __attribute__((ext_vector_type(8))) short short8;
typedef __attribute__((ext_vector_type(8))) _Float16 half8;
typedef __attribute__((ext_vector_type(4))) float f32x4;

__device__ inline unsigned short f2h(float f) {
  union { _Float16 h; unsigned short u; } c;
  c.h = (_Float16)f;                 // RNE
  return c.u;
}

__device__ inline void gl_lds16(const unsigned short* g, unsigned short* l) {
  __builtin_amdgcn_global_load_lds(
      (const __attribute__((address_space(1))) void*)g,
      (__attribute__((address_space(3))) void*)l, 16, 0, 0);
}

// ---- workspace layout (floats) ----
static const size_t UA_OFF_F  = 0;                                   // fp16 Ut attn [NQKV][NXc]
static const size_t UA_F_CNT  = ((size_t)NQKV * NXc + 1) / 2;
static const size_t UP_OFF_F  = UA_OFF_F + UA_F_CNT;                 // fp16 Ut proj [NXc][NXc]
static const size_t UP_F_CNT  = ((size_t)NXc * NXc + 1) / 2;
static const size_t QH_OFF_F  = UP_OFF_F + UP_F_CNT;                 // fp16 int q [B,H,S,64]
static const size_t HALF_CNT  = ((size_t)M_ * NXc + 1) / 2;
static const size_t KH_OFF_F  = QH_OFF_F + HALF_CNT;                 // fp16 int k [B,H,S,64]
static const size_t VHT_OFF_F = KH_OFF_F + HALF_CNT;                 // fp16 int v^T [B,H,64,S]
static const size_t AHF_OFF_F = VHT_OFF_F + HALF_CNT;                // fp16 attn out (xh earlier)
static const size_t SC_OFF    = AHF_OFF_F + HALF_CNT;
static const size_t WS_FLOATS_NEEDED = SC_OFF + 2;

// ---------------- max |tanh(w)| reduction ----------------
__global__ void k_maxtanh2(const float* __restrict__ wa, const float* __restrict__ wp,
                           unsigned int* __restrict__ out) {
  const int which = blockIdx.y;
  const float* w = which ? wp : wa;
  const int n = which ? (NXc * NXc) : (NXc * NQKV);
  float mx = 0.f;
  for (int i = blockIdx.x * blockDim.x + threadIdx.x; i < n;
       i += gridDim.x * blockDim.x)
    mx = fmaxf(mx, fabsf(tanhf(w[i])));
#pragma unroll
  for (int off = 32; off > 0; off >>= 1)
    mx = fmaxf(mx, __shfl_xor(mx, off));
  if ((threadIdx.x & 63) == 0)
    atomicMax(out + which, __float_as_uint(mx));
}

// ---------------- weight quant -> transposed exact-fp16 integer weights ------
__global__ __launch_bounds__(256) void k_quantw_t(
    const float* __restrict__ w, unsigned short* __restrict__ ut,
    int K, int N, const unsigned int* __restrict__ gmax_bits) {
  __shared__ unsigned short Ut[64][72];
  const float inv2m = 0.5f / __uint_as_float(*gmax_bits);
  const int k0 = blockIdx.y * 64, n0 = blockIdx.x * 64;
  const int t = threadIdx.x;
  const int r = t >> 4, c4 = (t & 15) * 4;
#pragma unroll
  for (int rr = 0; rr < 4; ++rr) {
    int row = rr * 16 + r;
    float4 f = *(const float4*)(w + (size_t)(k0 + row) * N + n0 + c4);
    float fv[4] = {f.x, f.y, f.z, f.w};
#pragma unroll
    for (int j = 0; j < 4; ++j) {
      float tq = tanhf(fv[j]) * inv2m + 0.5f;
      float u = 2.0f * rintf(tq * 255.0f) - 255.0f;
      Ut[c4 + j][row] = f2h(u);
    }
  }
  __syncthreads();
#pragma unroll
  for (int rep = 0; rep < 2; ++rep) {
    int c = t + rep * 256;
    int n = c >> 3, slot = c & 7;
    short8 v = *(const short8*)&Ut[n][slot * 8];
    *(short8*)(ut + (size_t)(n0 + n) * K + k0 + slot * 8) = v;
  }
}

// ---------------- x -> fp16 (once) ----------------
__global__ __launch_bounds__(256) void k_xhalf(
    const float* __restrict__ x, unsigned short* __restrict__ xh, int n8) {
  int i = blockIdx.x * 256 + threadIdx.x;
  if (i >= n8) return;
  const float* src = x + (size_t)i * 8;
  float4 f0 = *(const float4*)src;
  float4 f1 = *(const float4*)(src + 4);
  float fv[8] = {f0.x, f0.y, f0.z, f0.w, f1.x, f1.y, f1.z, f1.w};
  union { short8 v; unsigned short u[8]; } o;
#pragma unroll
  for (int j = 0; j < 8; ++j) o.u[j] = f2h(fv[j]);
  *(short8*)(xh + (size_t)i * 8) = o.v;
}

// ---------------- GEMM: 128x128, BK=32, 3-stage counted-vmcnt pipeline -------
// EPI 1 epilogue v2: ALL parts route through the LDS tile T for vectorized
// global stores. part 0/1: row-major T[row][col] (stride 136 -> aligned b128
// readback), 8 short8 stores (qh/kh) + 16 float4 (kq) per thread instead of
// 64/128 scalar scatters. part 2: transposed T (round 12 path). Quant math:
// y255 = rndne(med3(acc + 255*bias, 0, 255)) -- algebraically equal clamp.
template <int EPI>
__global__ __launch_bounds__(256, 3) void k_gemm3(
    const unsigned short* __restrict__ Ag, const unsigned short* __restrict__ Ug,
    const float* __restrict__ bias, float* __restrict__ Cout,
    unsigned short* __restrict__ qh, unsigned short* __restrict__ kh,
    unsigned short* __restrict__ vht, float* __restrict__ kq, float* __restrict__ vq,
    int nbn) {
  __shared__ __align__(16) unsigned short SMEM[3 * 4096 * 2];   // 48 KB
  unsigned short* Ahb3 = SMEM;
  unsigned short* Bsb3 = SMEM + 3 * 4096;
  unsigned short* T    = SMEM;                 // aliased after final barrier: [128][136]

  const int bid = blockIdx.x;
  const int cpx = gridDim.x >> 3;
  const int swz = (bid & 7) * cpx + (bid >> 3);
  const int bm = swz / nbn, bn = swz % nbn;
  const int part = (EPI == 1) ? (bn / 6) : 0;

  const int t = threadIdx.x;
  const int w = t >> 6, lane = t & 63;
  const int wm = w >> 1, wn = w & 1;
  const int g = lane >> 4, ln = lane & 15;

  const unsigned short* Ab = Ag + (size_t)bm * 128 * NXc;
  const unsigned short* Bb = Ug + (size_t)bn * 128 * NXc;

  const int srow = t >> 2;
  const int aco  = (((t & 3) ^ ((t >> 3) & 3)) << 3);
  const int rsw  = ((g ^ ((ln >> 1) & 3)) << 3);

  f32x4 acc[4][4];
#pragma unroll
  for (int i = 0; i < 4; ++i)
#pragma unroll
    for (int j = 0; j < 4; ++j) acc[i][j] = (f32x4)(0.f);

  auto STAGE = [&](int tk, int buf) {
    const int k0 = tk * 32;
    unsigned short* Ah = Ahb3 + buf * 4096;
    unsigned short* Bs = Bsb3 + buf * 4096;
    gl_lds16(Ab + (size_t)srow * NXc + k0 + aco, &Ah[t * 8]);
    gl_lds16(Ab + (size_t)(srow + 64) * NXc + k0 + aco, &Ah[(256 + t) * 8]);
    gl_lds16(Bb + (size_t)srow * NXc + k0 + aco, &Bs[t * 8]);
    gl_lds16(Bb + (size_t)(srow + 64) * NXc + k0 + aco, &Bs[(256 + t) * 8]);
  };
  auto COMPUTE = [&](int buf) {
    const unsigned short* Ah = Ahb3 + buf * 4096;
    const unsigned short* Bs = Bsb3 + buf * 4096;
    half8 bfrag[4];
#pragma unroll
    for (int nf = 0; nf < 4; ++nf)
      bfrag[nf] = *(const half8*)&Bs[(wn * 64 + nf * 16 + ln) * 32 + rsw];
#pragma unroll
    for (int mf = 0; mf < 4; ++mf) {
      half8 ah = *(const half8*)&Ah[(wm * 64 + mf * 16 + ln) * 32 + rsw];
#pragma unroll
      for (int nf = 0; nf < 4; ++nf)
        acc[mf][nf] = __builtin_amdgcn_mfma_f32_16x16x32_f16(ah, bfrag[nf], acc[mf][nf], 0, 0, 0);
    }
  };

  STAGE(0, 0);
  STAGE(1, 1);
  for (int tk = 0; tk < 22; ++tk) {
    asm volatile("s_waitcnt vmcnt(4)" ::: "memory");
    __builtin_amdgcn_s_barrier();
    __builtin_amdgcn_sched_barrier(0);
    STAGE(tk + 2, (tk + 2) % 3);
    COMPUTE(tk % 3);
  }
  asm volatile("s_waitcnt vmcnt(4)" ::: "memory");
  __builtin_amdgcn_s_barrier();
  __builtin_amdgcn_sched_barrier(0);
  COMPUTE(22 % 3);
  asm volatile("s_waitcnt vmcnt(0)" ::: "memory");
  __builtin_amdgcn_s_barrier();
  __builtin_amdgcn_sched_barrier(0);
  COMPUTE(23 % 3);

  const float inv255 = 1.0f / 255.0f;
  if (EPI == 0) {
#pragma unroll
    for (int mf = 0; mf < 4; ++mf) {
      int row0 = bm * 128 + wm * 64 + mf * 16 + g * 4;
#pragma unroll
      for (int nf = 0; nf < 4; ++nf) {
        int col = bn * 128 + wn * 64 + nf * 16 + ln;
        float bv = bias[col];
#pragma unroll
        for (int r = 0; r < 4; ++r)
          Cout[(size_t)(row0 + r) * NXc + col] = acc[mf][nf][r] * inv255 + bv;
      }
    }
  } else if (part == 2) {
    // v-part: vq coalesced directly; vht via transposed LDS + coalesced 16B.
    __syncthreads();                            // pipeline LDS reads complete
#pragma unroll
    for (int mf = 0; mf < 4; ++mf) {
      int row0 = bm * 128 + wm * 64 + mf * 16 + g * 4;
#pragma unroll
      for (int nf = 0; nf < 4; ++nf) {
        int col = bn * 128 + wn * 64 + nf * 16 + ln;
        float bv255 = bias[col] * 255.0f;
        int ff = col - 2 * NXc;
        int h = ff >> 6, d = ff & 63;
        int c = wn * 64 + nf * 16 + ln;
#pragma unroll
        for (int r = 0; r < 4; ++r) {
          float y255 = rintf(fminf(fmaxf(acc[mf][nf][r] + bv255, 0.f), 255.f));
          int row = row0 + r;
          int b = row >> 10, s = row & 1023;
          vq[(((size_t)b * H_ + h) * S_ + s) * HDc + d] = y255 * inv255;
          int sl = wm * 64 + mf * 16 + g * 4 + r;
          T[c * 136 + sl] = f2h(y255);
        }
      }
    }
    __syncthreads();
    const int bB = bm >> 3;
    const int s0 = (bm & 7) * 128;
    const int h0 = (bn - 12) * 2;
#pragma unroll
    for (int rep = 0; rep < 8; ++rep) {
      int idx = rep * 256 + t;
      int c = idx >> 4, sc = idx & 15;
      short8 v = *(const short8*)&T[c * 136 + sc * 8];
      int h = h0 + (c >> 6), d = c & 63;
      *(short8*)(vht + (((size_t)bB * H_ + h) * HDc + d) * S_ + s0 + sc * 8) = v;
    }
  } else {
    // q/k parts: row-major LDS tile, vectorized readback stores.
    __syncthreads();                            // pipeline LDS reads complete
#pragma unroll
    for (int mf = 0; mf < 4; ++mf) {
      int lrow0 = wm * 64 + mf * 16 + g * 4;
#pragma unroll
      for (int nf = 0; nf < 4; ++nf) {
        int lcol = wn * 64 + nf * 16 + ln;
        float bv255 = bias[bn * 128 + lcol] * 255.0f;
#pragma unroll
        for (int r = 0; r < 4; ++r) {
          float y255 = rintf(fminf(fmaxf(acc[mf][nf][r] + bv255, 0.f), 255.f));
          T[(lrow0 + r) * 136 + lcol] = f2h(y255);
        }
      }
    }
    __syncthreads();
#pragma unroll
    for (int rep = 0; rep < 8; ++rep) {
      int idx = rep * 256 + t;                  // 128 rows x 16 col-chunks
      int row = idx >> 4, cc = idx & 15;
      short8 v = *(const short8*)&T[row * 136 + cc * 8];
      int grow = bm * 128 + row;
      int b = grow >> 10, s = grow & 1023;
      int col = bn * 128 + cc * 8;
      int ff = col - part * NXc;
      int h = ff >> 6, d0 = ff & 63;            // d0 multiple of 8
      size_t dst = (((size_t)b * H_ + h) * S_ + s) * HDc + d0;
      if (part == 0) {
        *(short8*)(qh + dst) = v;
      } else {
        *(short8*)(kh + dst) = v;
        union { short8 s8; half8 h8; } cvt; cvt.s8 = v;
        float4 f0, f1;
        f0.x = (float)cvt.h8[0] * inv255; f0.y = (float)cvt.h8[1] * inv255;
        f0.z = (float)cvt.h8[2] * inv255; f0.w = (float)cvt.h8[3] * inv255;
        f1.x = (float)cvt.h8[4] * inv255; f1.y = (float)cvt.h8[5] * inv255;
        f1.z = (float)cvt.h8[6] * inv255; f1.w = (float)cvt.h8[7] * inv255;
        *(float4*)(kq + dst) = f0;
        *(float4*)(kq + dst + 4) = f1;
      }
    }
  }
}

// ---------------- MFMA causal flash attention (fp16, no-max softmax) ----------
__global__ __launch_bounds__(256) void k_attn_pair(
    const unsigned short* __restrict__ qh, const unsigned short* __restrict__ kh,
    const unsigned short* __restrict__ vht, unsigned short* __restrict__ ahf) {
  __shared__ __align__(16) unsigned short Ks[2][64 * 64];   // [kv][d]^((kv&7)<<3)
  __shared__ __align__(16) unsigned short Vt[2][64 * 64];   // [d][kv]^((d&7)<<3)
  __shared__ __align__(16) unsigned short Pp[4 * 16 * 64];  // per-wave P

  const int bid = blockIdx.x;                  // 768 = 8 xcd x 96
  const int gidx = (bid & 7) * 96 + (bid >> 3);
  const int hid = gidx >> 3;                   // head 0..95 (12 per XCD)
  const int p = gidx & 7;
  const int b = hid / H_, h = hid - b * H_;

  const size_t hoff = (size_t)hid * S_ * HDc;
  const unsigned short* qhp = qh + hoff;
  const unsigned short* khp = kh + hoff;
  const unsigned short* vhp = vht + hoff;

  const int t = threadIdx.x;
  const int w = t >> 6, lane = t & 63;
  const int g = lane >> 4, ln = lane & 15;

  const int r0 = t >> 3, c0 = (((t & 7) ^ (r0 & 7)) << 3);
  const int r1 = 32 + (t >> 3), c1 = (((t & 7) ^ (r1 & 7)) << 3);

  auto STAGE = [&](int jb, int buf) {
    gl_lds16(khp + (size_t)(jb * 64 + r0) * HDc + c0, &Ks[buf][t * 8]);
    gl_lds16(khp + (size_t)(jb * 64 + r1) * HDc + c1, &Ks[buf][(256 + t) * 8]);
    gl_lds16(vhp + (size_t)r0 * S_ + jb * 64 + c0, &Vt[buf][t * 8]);
    gl_lds16(vhp + (size_t)r1 * S_ + jb * 64 + c1, &Vt[buf][(256 + t) * 8]);
  };

  const float SCALE = 1.0f / (255.0f * 255.0f * 8.0f);

  int iq = p;
  half8 qfrag[2];
  {
    const unsigned short* qr = qhp + (size_t)(iq * 64 + w * 16 + ln) * HDc;
    qfrag[0] = *(const half8*)(qr + g * 8);
    qfrag[1] = *(const half8*)(qr + 32 + g * 8);
  }

  float l[4];
  f32x4 accO[4];
#pragma unroll
  for (int r = 0; r < 4; ++r) l[r] = 0.f;
#pragma unroll
  for (int nf = 0; nf < 4; ++nf) accO[nf] = (f32x4)(0.f);

  auto WRITEOUT = [&]() {
#pragma unroll
    for (int off = 1; off < 16; off <<= 1)
#pragma unroll
      for (int r = 0; r < 4; ++r) l[r] += __shfl_xor(l[r], off);
#pragma unroll
    for (int r = 0; r < 4; ++r) {
      float inv = 1.0f / (255.0f * l[r]);
      size_t row = (size_t)b * S_ + iq * 64 + w * 16 + g * 4 + r;
#pragma unroll
      for (int nf = 0; nf < 4; ++nf)
        ahf[row * NXc + h * HDc + nf * 16 + ln] = f2h(accO[nf][r] * inv);
    }
  };

  STAGE(0, 0);
  int jb = 0;
  for (int i = 0; i < 17; ++i) {
    const int buf = i & 1;
    __syncthreads();
    if (i + 1 < 17) {
      int njb = (i + 1 <= p) ? (i + 1) : (i - p);
      STAGE(njb, buf ^ 1);
    }

    f32x4 accS[4];
#pragma unroll
    for (int nf = 0; nf < 4; ++nf) accS[nf] = (f32x4)(0.f);
#pragma unroll
    for (int ks = 0; ks < 2; ++ks)
#pragma unroll
      for (int nf = 0; nf < 4; ++nf) {
        int kvr = nf * 16 + ln;
        half8 bk = *(const half8*)&Ks[buf][kvr * 64 + ((ks * 32 + g * 8) ^ ((kvr & 7) << 3))];
        accS[nf] = __builtin_amdgcn_mfma_f32_16x16x32_f16(qfrag[ks], bk, accS[nf], 0, 0, 0);
      }

    float pr[4][4];
    if (jb == iq) {
      const int grow = iq * 64 + w * 16 + g * 4;
      const int gcol = jb * 64 + ln;
#pragma unroll
      for (int nf = 0; nf < 4; ++nf)
#pragma unroll
        for (int r = 0; r < 4; ++r) {
          float pv = (gcol + nf * 16 > grow + r) ? 0.f : __expf(accS[nf][r] * SCALE);
          pr[nf][r] = pv;
          l[r] += pv;
        }
    } else {
#pragma unroll
      for (int nf = 0; nf < 4; ++nf)
#pragma unroll
        for (int r = 0; r < 4; ++r) {
          float pv = __expf(accS[nf][r] * SCALE);
          pr[nf][r] = pv;
          l[r] += pv;
        }
    }

#pragma unroll
    for (int nf = 0; nf < 4; ++nf)
#pragma unroll
      for (int r = 0; r < 4; ++r) {
        int prow = g * 4 + r;
        Pp[w * 1024 + prow * 64 + ((nf * 16 + ln) ^ ((prow & 7) << 3))] = f2h(pr[nf][r]);
      }

#pragma unroll
    for (int ks = 0; ks < 2; ++ks) {
      half8 pa = *(const half8*)&Pp[w * 1024 + ln * 64 + ((ks * 32 + g * 8) ^ ((ln & 7) << 3))];
#pragma unroll
      for (int nf = 0; nf < 4; ++nf) {
        int d = nf * 16 + ln;
        half8 bv = *(const half8*)&Vt[buf][d * 64 + ((ks * 32 + g * 8) ^ ((d & 7) << 3))];
        accO[nf] = __builtin_amdgcn_mfma_f32_16x16x32_f16(pa, bv, accO[nf], 0, 0, 0);
      }
    }

    if (i == p) {
      WRITEOUT();
#pragma unroll
      for (int r = 0; r < 4; ++r) l[r] = 0.f;
#pragma unroll
      for (int nf = 0; nf < 4; ++nf) accO[nf] = (f32x4)(0.f);
      iq = 15 - p;
      const unsigned short* qr2 = qhp + (size_t)(iq * 64 + w * 16 + ln) * HDc;
      qfrag[0] = *(const half8*)(qr2 + g * 8);
      qfrag[1] = *(const half8*)(qr2 + 32 + g * 8);
    } else if (i == 16) {
      WRITEOUT();
    }
    jb = (i + 1 <= p) ? (i + 1) : (i - p);
  }
}

// ---------------- host launcher ----------------
extern "C" void kernel_launch(void* const* d_in, const int* in_sizes, int n_in,
                              void* d_out, int out_size, void* d_ws, size_t ws_size,
                              hipStream_t stream) {
  const float* x      = (const float*)d_in[0];
  const float* W_attn = (const float*)d_in[1];
  const float* b_attn = (const float*)d_in[2];
  const float* W_proj = (const float*)d_in[3];
  const float* b_proj = (const float*)d_in[4];

  float* out = (float*)d_out;
  float* ws  = (float*)d_ws;
  if (ws_size < WS_FLOATS_NEEDED * sizeof(float)) return;

  float* a_out = out;                               // [B,S,NX]
  float* k_out = out + (size_t)M_ * NXc;            // present[0] = k
  float* v_out = k_out + (size_t)M_ * NXc;          // present[1] = v

  unsigned short* ua  = (unsigned short*)(ws + UA_OFF_F);
  unsigned short* up  = (unsigned short*)(ws + UP_OFF_F);
  unsigned short* qh  = (unsigned short*)(ws + QH_OFF_F);
  unsigned short* kh  = (unsigned short*)(ws + KH_OFF_F);
  unsigned short* vht = (unsigned short*)(ws + VHT_OFF_F);
  unsigned short* ahf = (unsigned short*)(ws + AHF_OFF_F);
  unsigned int* sc = (unsigned int*)(ws + SC_OFF);

  unsigned short* xh = ahf;   // region reuse: attn writes ahf only after qkv read xh

  hipMemsetAsync(sc, 0, 2 * sizeof(unsigned int), stream);

  k_maxtanh2<<<dim3(128, 2), 256, 0, stream>>>(W_attn, W_proj, sc);

  k_quantw_t<<<dim3(NQKV / 64, NXc / 64), 256, 0, stream>>>(W_attn, ua, NXc, NQKV, sc);
  k_quantw_t<<<dim3(NXc / 64, NXc / 64), 256, 0, stream>>>(W_proj, up, NXc, NXc, sc + 1);

  k_xhalf<<<(M_ * NXc / 8 + 255) / 256, 256, 0, stream>>>(x, xh, M_ * NXc / 8);

  // qkv = x @ wq_attn + b_attn (fp16 MFMA, counted-vmcnt pipeline, LDS epilogue)
  k_gemm3<1><<<(NQKV / 128) * (M_ / 128), 256, 0, stream>>>(
      xh, ua, b_attn, nullptr, qh, kh, vht, k_out, v_out, NQKV / 128);

  // causal attention (no-max softmax, head-chunked XCD swizzle)
  k_attn_pair<<<768, 256, 0, stream>>>(qh, kh, vht, ahf);

  // a = attn_out @ wq_proj + b_proj
  k_gemm3<0><<<(NXc / 128) * (M_ / 128), 256, 0, stream>>>(
      ahf, up, b_proj, a_out, nullptr, nullptr, nullptr, nullptr, nullptr, NXc / 128);
}